// Round 7
// baseline (813.316 us; speedup 1.0000x reference)
//
#include <hip/hip_runtime.h>
#include <hip/hip_cooperative_groups.h>

namespace cg = cooperative_groups;

// Inputs: floats fp32, ints int32. Outputs fp32 (verified round 7).
// Round 23: revert r22 regressions (aggemm packed-acc, attntail-256) to the
// measured r21 bodies; collapse ALL graph preprocessing into ONE cooperative
// kernel k_mega (1024 blocks x 256 thr, 4 blocks/CU co-resident):
//   phase Z: zero deg            -> grid.sync
//   phase A: count | Wt prep | LN1  (block-role split)  -> grid.sync
//   phase B: cursor (per-chunk redundant prefix + KS scan) -> grid.sync
//   phase C: place (8 edges/thread, batched atomics)
// 3 dispatches total: k_mega -> k_aggemm -> k_attntail.

typedef unsigned short ushort_t;
typedef __attribute__((ext_vector_type(8))) short bf16x8;   // 8 bf16 (MFMA A/B frag)
typedef __attribute__((ext_vector_type(4))) float floatx4;  // MFMA C/D frag

#define MEGA_BLOCKS 1024
#define CNT_BLOCKS  256

// ---------- helpers ----------
__device__ __forceinline__ float b2f(ushort_t u) {
    union { unsigned int i; float f; } v; v.i = ((unsigned int)u) << 16; return v.f;
}
__device__ __forceinline__ ushort_t f2b(float f) {
    union { float f; unsigned int i; } v; v.f = f;
    unsigned int x = v.i;
    return (ushort_t)((x + 0x7FFFu + ((x >> 16) & 1u)) >> 16);   // RTNE
}
__device__ __forceinline__ float gelu_f(float x) {
    return 0.5f * x * (1.0f + erff(x * 0.70710678118654752440f)); // exact gelu
}
__device__ __forceinline__ float waveReduceSum(float v) {
#pragma unroll
    for (int o = 32; o; o >>= 1) v += __shfl_xor(v, o, 64);
    return v;
}
__device__ __forceinline__ int waveReduceSumI(int v) {
#pragma unroll
    for (int o = 32; o; o >>= 1) v += __shfl_xor(v, o, 64);
    return v;
}
__device__ __forceinline__ float waveReduceMax(float v) {
#pragma unroll
    for (int o = 32; o; o >>= 1) v = fmaxf(v, __shfl_xor(v, o, 64));
    return v;
}
__device__ __forceinline__ int lowerBound(const int* __restrict__ a, int n, int v) {
    int lo = 0, hi = n;
    while (lo < hi) { int mid = (lo + hi) >> 1; if (a[mid] < v) lo = mid + 1; else hi = mid; }
    return lo;
}
__device__ __forceinline__ void acc8(float* a, const bf16x8& r) {
    a[0] += b2f((ushort_t)r[0]); a[1] += b2f((ushort_t)r[1]);
    a[2] += b2f((ushort_t)r[2]); a[3] += b2f((ushort_t)r[3]);
    a[4] += b2f((ushort_t)r[4]); a[5] += b2f((ushort_t)r[5]);
    a[6] += b2f((ushort_t)r[6]); a[7] += b2f((ushort_t)r[7]);
}

// ---------- 1. cooperative mega: zero -> (count | prep | LN) -> cursor -> place ----
__global__ void __launch_bounds__(256, 4) k_mega(
    const float* __restrict__ x, const float* __restrict__ w, const float* __restrict__ b,
    const float* __restrict__ Wl, const float* __restrict__ Wr,
    const int* __restrict__ ei, int* __restrict__ deg,
    int* __restrict__ cursor, int* __restrict__ wcur, int* __restrict__ nbr,
    ushort_t* __restrict__ Wt, ushort_t* __restrict__ hb,
    int N, int E, int nch) {
    cg::grid_group grid = cg::this_grid();
    __shared__ int sb[256];
    __shared__ int cw[4];
    int bid = blockIdx.x, t = threadIdx.x;
    int nblk = (int)gridDim.x;

    // ---- phase Z: zero deg ----
    for (int i = bid * 256 + t; i < N; i += nblk * 256) deg[i] = 0;
    __threadfence();
    grid.sync();

    // ---- phase A: count (blocks 0..CNT) | Wt prep (next 128) | LN1 (rest) ----
    if (bid < CNT_BLOCKS) {
        const int* dstp = ei + E;
        int stride = CNT_BLOCKS * 256 * 8;
        for (int i0 = (bid * 256 + t) * 8; i0 < E; i0 += stride) {
            if (i0 + 7 < E) {
                int4 a = *(const int4*)(dstp + i0);
                int4 c = *(const int4*)(dstp + i0 + 4);
                atomicAdd(&deg[a.x], 1); atomicAdd(&deg[a.y], 1);
                atomicAdd(&deg[a.z], 1); atomicAdd(&deg[a.w], 1);
                atomicAdd(&deg[c.x], 1); atomicAdd(&deg[c.y], 1);
                atomicAdd(&deg[c.z], 1); atomicAdd(&deg[c.w], 1);
            } else {
                int e1 = min(i0 + 8, E);
                for (int i = i0; i < e1; i++) atomicAdd(&deg[dstp[i]], 1);
            }
        }
    } else if (bid < CNT_BLOCKS + 128) {
        int id = (bid - CNT_BLOCKS) * 256 + t;       // exactly 32768 threads
        int n = id >> 8, k = id & 255;
        float v = (k < 128) ? Wl[k * 128 + n] : Wr[(k - 128) * 128 + n];
        Wt[n * 256 + k] = f2b(v);
    } else {
        int lnb = bid - (CNT_BLOCKS + 128);
        int nLN = nblk - (CNT_BLOCKS + 128);         // 640 blocks
        int lane = t & 63;
        for (int base = lnb * 4; base < N; base += nLN * 4) {
            int row = base + (t >> 6);
            if (row >= N) continue;
            size_t rb = (size_t)row * 128;
            float2 xv = ((const float2*)(x + rb))[lane];
            float v0 = xv.x, v1 = xv.y;
            float s  = waveReduceSum(v0 + v1);
            float s2 = waveReduceSum(v0 * v0 + v1 * v1);
            float mu = s * (1.0f / 128.0f);
            float var = s2 * (1.0f / 128.0f) - mu * mu;
            float rstd = 1.0f / sqrtf(var + 1e-5f);
            int d = lane * 2;
            ushort2 ov;
            ov.x = f2b((v0 - mu) * rstd * w[d]     + b[d]);
            ov.y = f2b((v1 - mu) * rstd * w[d + 1] + b[d + 1]);
            ((ushort2*)(hb + rb))[lane] = ov;
        }
    }
    __threadfence();
    grid.sync();

    // ---- phase B: cursor (chunk c = bid, only bid < nch active) ----
    if (bid < nch) {
        int c = bid;
        int lim = c << 8;
        int part = 0;
        for (int j = t; j < lim; j += 256) part += deg[j];
        part = waveReduceSumI(part);
        int lane = t & 63, wv = t >> 6;
        if (lane == 0) cw[wv] = part;
        int i = (c << 8) + t;
        int v = (i < N) ? deg[i] : 0;
        sb[t] = v;
        __syncthreads();
        for (int o = 1; o < 256; o <<= 1) {
            int a = (t >= o) ? sb[t - o] : 0;
            __syncthreads();
            sb[t] += a;
            __syncthreads();
        }
        int coff = cw[0] + cw[1] + cw[2] + cw[3];
        if (i < N) {
            int cv = sb[t] - v + coff;     // exclusive scan = row start
            cursor[i] = cv;
            wcur[i]   = cv;
        }
    }
    __threadfence();
    grid.sync();

    // ---- phase C: place (8 edges/thread, batched atomics, grid-stride) ----
    {
        int stride = nblk * 256 * 8;
        for (int i0 = (bid * 256 + t) * 8; i0 < E; i0 += stride) {
            if (i0 + 7 < E) {
                int4 s0 = *(const int4*)(ei + i0);
                int4 s1 = *(const int4*)(ei + i0 + 4);
                int4 d0 = *(const int4*)(ei + E + i0);
                int4 d1 = *(const int4*)(ei + E + i0 + 4);
                int p0 = atomicAdd(&wcur[d0.x], 1);
                int p1 = atomicAdd(&wcur[d0.y], 1);
                int p2 = atomicAdd(&wcur[d0.z], 1);
                int p3 = atomicAdd(&wcur[d0.w], 1);
                int p4 = atomicAdd(&wcur[d1.x], 1);
                int p5 = atomicAdd(&wcur[d1.y], 1);
                int p6 = atomicAdd(&wcur[d1.z], 1);
                int p7 = atomicAdd(&wcur[d1.w], 1);
                nbr[p0] = s0.x; nbr[p1] = s0.y; nbr[p2] = s0.z; nbr[p3] = s0.w;
                nbr[p4] = s1.x; nbr[p5] = s1.y; nbr[p6] = s1.z; nbr[p7] = s1.w;
            } else {
                int e1 = min(i0 + 8, E);
                for (int i = i0; i < e1; i++) {
                    int s = ei[i], d = ei[E + i];
                    nbr[atomicAdd(&wcur[d], 1)] = s;
                }
            }
        }
    }
}

// ---------- 2. fused: CSR mean-gather -> MFMA GEMM -> LN -> gelu -> gate ----------
__global__ void __launch_bounds__(256) k_aggemm(
    const ushort_t* __restrict__ hb, const ushort_t* __restrict__ Wt,
    const float* __restrict__ bl, const float* __restrict__ lnw,
    const float* __restrict__ lnb, const float* __restrict__ gw,
    const float* __restrict__ gb, const int* __restrict__ deg,
    const int* __restrict__ cursor, const int* __restrict__ nbr,
    ushort_t* __restrict__ h3b, float* __restrict__ gate, int N) {
    __shared__ ushort_t A[16][264];   // [m][k], pad 264
    __shared__ float H2[16][132];
    int t = threadIdx.x;
    int row0 = blockIdx.x * 16;
    int w = t >> 6, l = t & 63;
    int sub = l >> 4, li = l & 15;
    // ---- phase 0: each subgroup aggregates its own node (row r = w*4+sub) ----
    {
        int r = w * 4 + sub;
        int node = row0 + r; if (node >= N) node = N - 1;
        bf16x8 hv = *(const bf16x8*)(hb + (size_t)node * 128 + li * 8);
        *(bf16x8*)&A[r][128 + li * 8] = hv;
        int dg = deg[node];
        int st = cursor[node];
        float a[8] = {0.f, 0.f, 0.f, 0.f, 0.f, 0.f, 0.f, 0.f};
        int j = 0;
        for (; j + 8 <= dg; j += 8) {        // 8 independent row loads in flight
            int s0 = nbr[st + j],     s1 = nbr[st + j + 1];
            int s2 = nbr[st + j + 2], s3 = nbr[st + j + 3];
            int s4 = nbr[st + j + 4], s5 = nbr[st + j + 5];
            int s6 = nbr[st + j + 6], s7 = nbr[st + j + 7];
            bf16x8 r0 = *(const bf16x8*)(hb + (size_t)s0 * 128 + li * 8);
            bf16x8 r1 = *(const bf16x8*)(hb + (size_t)s1 * 128 + li * 8);
            bf16x8 r2 = *(const bf16x8*)(hb + (size_t)s2 * 128 + li * 8);
            bf16x8 r3 = *(const bf16x8*)(hb + (size_t)s3 * 128 + li * 8);
            bf16x8 r4 = *(const bf16x8*)(hb + (size_t)s4 * 128 + li * 8);
            bf16x8 r5 = *(const bf16x8*)(hb + (size_t)s5 * 128 + li * 8);
            bf16x8 r6 = *(const bf16x8*)(hb + (size_t)s6 * 128 + li * 8);
            bf16x8 r7 = *(const bf16x8*)(hb + (size_t)s7 * 128 + li * 8);
            acc8(a, r0); acc8(a, r1); acc8(a, r2); acc8(a, r3);
            acc8(a, r4); acc8(a, r5); acc8(a, r6); acc8(a, r7);
        }
        for (; j + 4 <= dg; j += 4) {
            int s0 = nbr[st + j],     s1 = nbr[st + j + 1];
            int s2 = nbr[st + j + 2], s3 = nbr[st + j + 3];
            bf16x8 r0 = *(const bf16x8*)(hb + (size_t)s0 * 128 + li * 8);
            bf16x8 r1 = *(const bf16x8*)(hb + (size_t)s1 * 128 + li * 8);
            bf16x8 r2 = *(const bf16x8*)(hb + (size_t)s2 * 128 + li * 8);
            bf16x8 r3 = *(const bf16x8*)(hb + (size_t)s3 * 128 + li * 8);
            acc8(a, r0); acc8(a, r1); acc8(a, r2); acc8(a, r3);
        }
        for (; j < dg; j++) {
            int s = nbr[st + j];
            bf16x8 r0 = *(const bf16x8*)(hb + (size_t)s * 128 + li * 8);
            acc8(a, r0);
        }
        float inv = 1.0f / fmaxf((float)dg, 1.0f);
        bf16x8 ov;
        ov[0] = (short)f2b(a[0] * inv); ov[1] = (short)f2b(a[1] * inv);
        ov[2] = (short)f2b(a[2] * inv); ov[3] = (short)f2b(a[3] * inv);
        ov[4] = (short)f2b(a[4] * inv); ov[5] = (short)f2b(a[5] * inv);
        ov[6] = (short)f2b(a[6] * inv); ov[7] = (short)f2b(a[7] * inv);
        *(bf16x8*)&A[r][li * 8] = ov;
    }
    __syncthreads();
    // ---- phase 1: MFMA over K=256 ----
    int m16 = l & 15, quad = l >> 4;
    int n0 = w * 32 + m16;
    int n1 = n0 + 16;
    floatx4 acc0 = {0.f, 0.f, 0.f, 0.f}, acc1 = {0.f, 0.f, 0.f, 0.f};
    for (int ks = 0; ks < 256; ks += 32) {
        bf16x8 a  = *(const bf16x8*)&A[m16][ks + quad * 8];
        bf16x8 b0 = *(const bf16x8*)(Wt + (size_t)n0 * 256 + ks + quad * 8);
        bf16x8 b1 = *(const bf16x8*)(Wt + (size_t)n1 * 256 + ks + quad * 8);
        acc0 = __builtin_amdgcn_mfma_f32_16x16x32_bf16(a, b0, acc0, 0, 0, 0);
        acc1 = __builtin_amdgcn_mfma_f32_16x16x32_bf16(a, b1, acc1, 0, 0, 0);
    }
#pragma unroll
    for (int i = 0; i < 4; i++) {
        H2[quad * 4 + i][n0] = acc0[i];
        H2[quad * 4 + i][n1] = acc1[i];
    }
    __syncthreads();
    // ---- phase 2: +bias, LN, gelu, gate; h3 -> h3b ----
    int d = l * 2;
    float bb0 = bl[d],  bb1 = bl[d + 1];
    float lw0 = lnw[d], lw1 = lnw[d + 1];
    float lb0 = lnb[d], lb1 = lnb[d + 1];
    float gw0 = gw[d],  gw1 = gw[d + 1];
    float gbias = gb[0];
#pragma unroll
    for (int rr = 0; rr < 4; rr++) {
        int r = w * 4 + rr;
        int row = row0 + r;
        if (row >= N) break;
        float v0 = H2[r][d] + bb0, v1 = H2[r][d + 1] + bb1;
        float s  = waveReduceSum(v0 + v1);
        float s2 = waveReduceSum(v0 * v0 + v1 * v1);
        float mu = s * (1.f / 128.f);
        float var = s2 * (1.f / 128.f) - mu * mu;
        float rstd = 1.0f / sqrtf(var + 1e-5f);
        float g0 = gelu_f((v0 - mu) * rstd * lw0 + lb0);
        float g1 = gelu_f((v1 - mu) * rstd * lw1 + lb1);
        float gp = waveReduceSum(g0 * gw0 + g1 * gw1);
        ushort2 ov; ov.x = f2b(g0); ov.y = f2b(g1);
        ((ushort2*)(h3b + (size_t)row * 128))[l] = ov;
        if (l == 0) gate[row] = gp + gbias;
    }
}

// ---------- 3. fused: segment bounds (binary search) + softmax pool + head ----------
__global__ void __launch_bounds__(128) k_attntail(
    const float* __restrict__ gate, const ushort_t* __restrict__ h3b,
    const int* __restrict__ batch,
    const float* __restrict__ text, const float* __restrict__ feats,
    const float* __restrict__ msgW, const float* __restrict__ msgb,
    const float* __restrict__ featW, const float* __restrict__ featb,
    const float* __restrict__ gwt, const float* __restrict__ mixw,
    const float* __restrict__ mixb, const float* __restrict__ fc1W,
    const float* __restrict__ fc1b,
    float* __restrict__ ge_out, float* __restrict__ attn_out,
    float* __restrict__ logits, int N, int G) {
    int g = blockIdx.x, t = threadIdx.x;
    __shared__ int sbound[2];
    __shared__ float wbuf[2];
    __shared__ float pbuf[128];
    __shared__ float txt[768];
    __shared__ float rbuf[4];
    if (t < 2) sbound[t] = lowerBound(batch, N, g + t);
    for (int i = t; i < 768; i += 128) txt[i] = text[(size_t)g * 768 + i];
    __syncthreads();
    int s0 = sbound[0], s1 = sbound[1];
    int lane = t & 63, wv = t >> 6;
    float acc = 0.f;
    if (s1 > s0) {                       // block-uniform branch
        float m = -3.0e38f;
        for (int i = s0 + t; i < s1; i += 128) m = fmaxf(m, gate[i]);
        m = waveReduceMax(m);
        if (lane == 0) wbuf[wv] = m;
        __syncthreads();
        m = fmaxf(wbuf[0], wbuf[1]);
        __syncthreads();
        float dsum = 0.f;
        for (int i = s0 + t; i < s1; i += 128) dsum += expf(gate[i] - m);
        dsum = waveReduceSum(dsum);
        if (lane == 0) wbuf[wv] = dsum;
        __syncthreads();
        float inv = 1.0f / (wbuf[0] + wbuf[1]);
        for (int base = s0; base < s1; base += 128) {
            int n = min(128, s1 - base);
            __syncthreads();
            if (t < n) {
                float p = expf(gate[base + t] - m) * inv;
                pbuf[t] = p;
                attn_out[base + t] = p;
            }
            __syncthreads();
            for (int j = 0; j < n; j++)
                acc += pbuf[j] * b2f(h3b[(size_t)(base + j) * 128 + t]);
        }
    }
    ge_out[(size_t)g * 128 + t] = acc;
    // ---- head ----
    float am = msgb[t];
    for (int k = 0; k < 768; k += 4) {
        float4 a = *(const float4*)&txt[k];
        am += a.x * msgW[(k + 0) * 128 + t] + a.y * msgW[(k + 1) * 128 + t]
            + a.z * msgW[(k + 2) * 128 + t] + a.w * msgW[(k + 3) * 128 + t];
    }
    float me = gelu_f(am);
    float af = featb[t];
#pragma unroll
    for (int k = 0; k < 14; k++) af += feats[g * 14 + k] * featW[k * 128 + t];
    float fe = gelu_f(af);
    float e0 = gwt[0] * acc;
    float ps = e0 + me + fe, ps2 = e0 * e0 + me * me + fe * fe;
    float r1 = waveReduceSum(ps), r2 = waveReduceSum(ps2);
    __syncthreads();
    if (lane == 0) { rbuf[wv] = r1; rbuf[2 + wv] = r2; }
    __syncthreads();
    float S = rbuf[0] + rbuf[1], S2 = rbuf[2] + rbuf[3];
    float mu = S * (1.f / 384.f);
    float var = S2 * (1.f / 384.f) - mu * mu;
    float rstd = 1.0f / sqrtf(var + 1e-5f);
    float n0 = (e0 - mu) * rstd * mixw[t]       + mixb[t];
    float n1 = (me - mu) * rstd * mixw[128 + t] + mixb[128 + t];
    float n2 = (fe - mu) * rstd * mixw[256 + t] + mixb[256 + t];
    float lp = n0 * fc1W[t] + n1 * fc1W[128 + t] + n2 * fc1W[256 + t];
    float r3 = waveReduceSum(lp);
    __syncthreads();
    if (lane == 0) rbuf[wv] = r3;
    __syncthreads();
    if (t == 0) logits[g] = rbuf[0] + rbuf[1] + fc1b[0];
}

// ---------- launch ----------
extern "C" void kernel_launch(void* const* d_in, const int* in_sizes, int n_in,
                              void* d_out, int out_size, void* d_ws, size_t ws_size,
                              hipStream_t stream) {
    const float* x     = (const float*)d_in[0];
    const int*   ei    = (const int*)d_in[1];
    const int*   batch = (const int*)d_in[2];
    const float* text  = (const float*)d_in[4];
    const float* feats = (const float*)d_in[5];
    const float* lnpw  = (const float*)d_in[6];
    const float* lnpb  = (const float*)d_in[7];
    const float* Wl    = (const float*)d_in[8];
    const float* bl    = (const float*)d_in[9];
    const float* Wr    = (const float*)d_in[10];
    const float* lncw  = (const float*)d_in[11];
    const float* lncb  = (const float*)d_in[12];
    const float* gatew = (const float*)d_in[13];
    const float* gateb = (const float*)d_in[14];
    const float* gwt   = (const float*)d_in[15];
    const float* msgW  = (const float*)d_in[16];
    const float* msgb  = (const float*)d_in[17];
    const float* featW = (const float*)d_in[18];
    const float* featb = (const float*)d_in[19];
    const float* mixw  = (const float*)d_in[20];
    const float* mixb  = (const float*)d_in[21];
    const float* fc1W  = (const float*)d_in[22];
    const float* fc1b  = (const float*)d_in[23];

    int N = in_sizes[0] / 128;
    int E = in_sizes[1] / 2;
    int G = in_sizes[4] / 768;

    char* wp = (char*)d_ws;
    auto alloc = [&](size_t bytes) -> char* {
        char* p = wp; wp += (bytes + 255) & ~(size_t)255; return p;
    };
    ushort_t* hb     = (ushort_t*)alloc((size_t)N * 128 * 2);   // h (bf16)
    ushort_t* h3b    = (ushort_t*)alloc((size_t)N * 128 * 2);   // h3 (bf16) from aggemm
    ushort_t* Wt     = (ushort_t*)alloc(128 * 256 * 2);
    float*    gate   = (float*)alloc((size_t)N * 4);
    int*      deg    = (int*)alloc((size_t)N * 4);
    int*      cursor = (int*)alloc((size_t)N * 4);
    int*      wcur   = (int*)alloc((size_t)N * 4);
    int*      nbr    = (int*)alloc((size_t)E * 4);

    int nch = (N + 255) / 256;    // 196 chunks of 256 nodes

    // OUTPUTS fp32, flat in return order:
    float* logits_out = (float*)d_out;                 // [G, 1]
    float* ge_out     = logits_out + G;                // [G, 128]
    float* attn_out   = ge_out + (size_t)G * 128;      // [N, 1]

    // ---- cooperative mega launch ----
    void* kargs[] = {
        (void*)&x, (void*)&lnpw, (void*)&lnpb, (void*)&Wl, (void*)&Wr,
        (void*)&ei, (void*)&deg, (void*)&cursor, (void*)&wcur, (void*)&nbr,
        (void*)&Wt, (void*)&hb, (void*)&N, (void*)&E, (void*)&nch
    };
    hipLaunchCooperativeKernel((const void*)k_mega, dim3(MEGA_BLOCKS), dim3(256),
                               kargs, 0, stream);

    k_aggemm   <<<(N + 15) / 16, 256, 0, stream>>>(hb, Wt, bl, lncw, lncb, gatew, gateb,
                                                   deg, cursor, nbr, h3b, gate, N);
    k_attntail <<<G,             128, 0, stream>>>(gate, h3b, batch, text, feats,
                                                   msgW, msgb, featW, featb, gwt,
                                                   mixw, mixb, fc1W, fc1b,
                                                   ge_out, attn_out, logits_out, N, G);
}

// Round 8
// 309.626 us; speedup vs baseline: 2.6268x; 2.6268x over previous
//
#include <hip/hip_runtime.h>

// Inputs: floats fp32, ints int32. Outputs fp32 (verified round 7).
// Round 24: revert r23 cooperative disaster (grid.sync ~100us each on 8-XCD).
// Base = round-21/r5 config (306 us measured). Two surgical changes:
//   - k_attntail: PV inner loop unrolled x4 with 4 independent accumulators
//     (breaks the ~98-step dependent FMA chain, 4 row-loads in flight).
//   - k_place: 16 edges/thread (16 atomics batched before 16 stores).
// Everything else byte-identical to the 306-us round-5 kernel.

typedef unsigned short ushort_t;
typedef __attribute__((ext_vector_type(8))) short bf16x8;   // 8 bf16 (MFMA A/B frag)
typedef __attribute__((ext_vector_type(4))) float floatx4;  // MFMA C/D frag

// ---------- helpers ----------
__device__ __forceinline__ float b2f(ushort_t u) {
    union { unsigned int i; float f; } v; v.i = ((unsigned int)u) << 16; return v.f;
}
__device__ __forceinline__ ushort_t f2b(float f) {
    union { float f; unsigned int i; } v; v.f = f;
    unsigned int x = v.i;
    return (ushort_t)((x + 0x7FFFu + ((x >> 16) & 1u)) >> 16);   // RTNE
}
__device__ __forceinline__ float gelu_f(float x) {
    return 0.5f * x * (1.0f + erff(x * 0.70710678118654752440f)); // exact gelu
}
__device__ __forceinline__ float waveReduceSum(float v) {
#pragma unroll
    for (int o = 32; o; o >>= 1) v += __shfl_xor(v, o, 64);
    return v;
}
__device__ __forceinline__ int waveReduceSumI(int v) {
#pragma unroll
    for (int o = 32; o; o >>= 1) v += __shfl_xor(v, o, 64);
    return v;
}
__device__ __forceinline__ float waveReduceMax(float v) {
#pragma unroll
    for (int o = 32; o; o >>= 1) v = fmaxf(v, __shfl_xor(v, o, 64));
    return v;
}
__device__ __forceinline__ int lowerBound(const int* __restrict__ a, int n, int v) {
    int lo = 0, hi = n;
    while (lo < hi) { int mid = (lo + hi) >> 1; if (a[mid] < v) lo = mid + 1; else hi = mid; }
    return lo;
}
__device__ __forceinline__ void acc8(float* a, const bf16x8& r) {
    a[0] += b2f((ushort_t)r[0]); a[1] += b2f((ushort_t)r[1]);
    a[2] += b2f((ushort_t)r[2]); a[3] += b2f((ushort_t)r[3]);
    a[4] += b2f((ushort_t)r[4]); a[5] += b2f((ushort_t)r[5]);
    a[6] += b2f((ushort_t)r[6]); a[7] += b2f((ushort_t)r[7]);
}

// ---------- 1. fused: edge count (0..ebc) | Wt prep (+128) | LN1 (rest) ----------
__global__ void __launch_bounds__(256) k_cpl(
    const float* __restrict__ x, const float* __restrict__ w, const float* __restrict__ b,
    const float* __restrict__ Wl, const float* __restrict__ Wr,
    const int* __restrict__ ei, int* __restrict__ deg,
    ushort_t* __restrict__ Wt, ushort_t* __restrict__ hb, int N, int E, int ebc) {
    int bid = blockIdx.x;
    if (bid < ebc) {             // ---- count role: 8 edges/thread, int4 x2
        int i0 = (bid * 256 + threadIdx.x) * 8;
        const int* dstp = ei + E;
        if (i0 + 7 < E) {
            int4 a = *(const int4*)(dstp + i0);
            int4 c = *(const int4*)(dstp + i0 + 4);
            atomicAdd(&deg[a.x], 1); atomicAdd(&deg[a.y], 1);
            atomicAdd(&deg[a.z], 1); atomicAdd(&deg[a.w], 1);
            atomicAdd(&deg[c.x], 1); atomicAdd(&deg[c.y], 1);
            atomicAdd(&deg[c.z], 1); atomicAdd(&deg[c.w], 1);
        } else {
            int e1 = min(i0 + 8, E);
            for (int i = i0; i < e1; i++) atomicAdd(&deg[dstp[i]], 1);
        }
        return;
    }
    bid -= ebc;
    if (bid < 128) {             // ---- prep role: Wt[n][k] = bf16 concat-T of Wl;Wr
        int id = bid * 256 + threadIdx.x;        // exactly 32768 threads
        int n = id >> 8, k = id & 255;
        float v = (k < 128) ? Wl[k * 128 + n] : Wr[(k - 128) * 128 + n];
        Wt[n * 256 + k] = f2b(v);
        return;
    }
    int lb = bid - 128;          // ---- ln1 role: 4 rows per block, 1 wave per row
    int row  = lb * 4 + (threadIdx.x >> 6);
    int lane = threadIdx.x & 63;
    if (row >= N) return;
    size_t base = (size_t)row * 128;
    float2 xv = ((const float2*)(x + base))[lane];
    float v0 = xv.x, v1 = xv.y;
    float s  = waveReduceSum(v0 + v1);
    float s2 = waveReduceSum(v0 * v0 + v1 * v1);
    float mu = s * (1.0f / 128.0f);
    float var = s2 * (1.0f / 128.0f) - mu * mu;
    float rstd = 1.0f / sqrtf(var + 1e-5f);
    int d = lane * 2;
    ushort2 ov;
    ov.x = f2b((v0 - mu) * rstd * w[d]     + b[d]);
    ov.y = f2b((v1 - mu) * rstd * w[d + 1] + b[d + 1]);
    ((ushort2*)(hb + base))[lane] = ov;
}

// ---------- 2. cursor: redundant prefix reduce + Kogge-Stone scan -> cursor,wcur ----
__global__ void __launch_bounds__(256) k_cursor3(
    const int* __restrict__ deg, int* __restrict__ cursor, int* __restrict__ wcur, int N) {
    int c = blockIdx.x, t = threadIdx.x;
    __shared__ int sb[256];
    __shared__ int cw[4];
    int lim = c << 8;
    int part = 0;
    for (int j = t; j < lim; j += 256) part += deg[j];
    part = waveReduceSumI(part);
    int lane = t & 63, wv = t >> 6;
    if (lane == 0) cw[wv] = part;
    int i = (c << 8) + t;
    int v = (i < N) ? deg[i] : 0;
    sb[t] = v;
    __syncthreads();
    for (int o = 1; o < 256; o <<= 1) {
        int a = (t >= o) ? sb[t - o] : 0;
        __syncthreads();
        sb[t] += a;
        __syncthreads();
    }
    int coff = cw[0] + cw[1] + cw[2] + cw[3];
    if (i < N) {
        int cv = sb[t] - v + coff;     // exclusive scan = row start
        cursor[i] = cv;
        wcur[i]   = cv;
    }
}

// ---------- 3. direct placement: 16 edges/thread, atomics batched before stores -----
__global__ void __launch_bounds__(256) k_place(
    const int* __restrict__ ei, int* __restrict__ wcur, int* __restrict__ nbr, int E) {
    int i0 = (blockIdx.x * 256 + threadIdx.x) * 16;
    if (i0 + 15 < E) {
        int4 s0 = *(const int4*)(ei + i0);
        int4 s1 = *(const int4*)(ei + i0 + 4);
        int4 s2 = *(const int4*)(ei + i0 + 8);
        int4 s3 = *(const int4*)(ei + i0 + 12);
        int4 d0 = *(const int4*)(ei + E + i0);
        int4 d1 = *(const int4*)(ei + E + i0 + 4);
        int4 d2 = *(const int4*)(ei + E + i0 + 8);
        int4 d3 = *(const int4*)(ei + E + i0 + 12);
        int p0  = atomicAdd(&wcur[d0.x], 1);
        int p1  = atomicAdd(&wcur[d0.y], 1);
        int p2  = atomicAdd(&wcur[d0.z], 1);
        int p3  = atomicAdd(&wcur[d0.w], 1);
        int p4  = atomicAdd(&wcur[d1.x], 1);
        int p5  = atomicAdd(&wcur[d1.y], 1);
        int p6  = atomicAdd(&wcur[d1.z], 1);
        int p7  = atomicAdd(&wcur[d1.w], 1);
        int p8  = atomicAdd(&wcur[d2.x], 1);
        int p9  = atomicAdd(&wcur[d2.y], 1);
        int p10 = atomicAdd(&wcur[d2.z], 1);
        int p11 = atomicAdd(&wcur[d2.w], 1);
        int p12 = atomicAdd(&wcur[d3.x], 1);
        int p13 = atomicAdd(&wcur[d3.y], 1);
        int p14 = atomicAdd(&wcur[d3.z], 1);
        int p15 = atomicAdd(&wcur[d3.w], 1);
        nbr[p0]  = s0.x; nbr[p1]  = s0.y; nbr[p2]  = s0.z; nbr[p3]  = s0.w;
        nbr[p4]  = s1.x; nbr[p5]  = s1.y; nbr[p6]  = s1.z; nbr[p7]  = s1.w;
        nbr[p8]  = s2.x; nbr[p9]  = s2.y; nbr[p10] = s2.z; nbr[p11] = s2.w;
        nbr[p12] = s3.x; nbr[p13] = s3.y; nbr[p14] = s3.z; nbr[p15] = s3.w;
    } else {
        int e1 = min(i0 + 16, E);
        for (int i = i0; i < e1; i++) {
            int s = ei[i], d = ei[E + i];
            nbr[atomicAdd(&wcur[d], 1)] = s;
        }
    }
}

// ---------- 4. fused: CSR mean-gather -> MFMA GEMM -> LN -> gelu -> gate ----------
__global__ void __launch_bounds__(256) k_aggemm(
    const ushort_t* __restrict__ hb, const ushort_t* __restrict__ Wt,
    const float* __restrict__ bl, const float* __restrict__ lnw,
    const float* __restrict__ lnb, const float* __restrict__ gw,
    const float* __restrict__ gb, const int* __restrict__ deg,
    const int* __restrict__ cursor, const int* __restrict__ nbr,
    ushort_t* __restrict__ h3b, float* __restrict__ gate, int N) {
    __shared__ ushort_t A[16][264];   // [m][k], pad 264
    __shared__ float H2[16][132];
    int t = threadIdx.x;
    int row0 = blockIdx.x * 16;
    int w = t >> 6, l = t & 63;
    int sub = l >> 4, li = l & 15;
    // ---- phase 0: each subgroup aggregates its own node (row r = w*4+sub) ----
    {
        int r = w * 4 + sub;
        int node = row0 + r; if (node >= N) node = N - 1;
        bf16x8 hv = *(const bf16x8*)(hb + (size_t)node * 128 + li * 8);
        *(bf16x8*)&A[r][128 + li * 8] = hv;
        int dg = deg[node];
        int st = cursor[node];
        float a[8] = {0.f, 0.f, 0.f, 0.f, 0.f, 0.f, 0.f, 0.f};
        int j = 0;
        for (; j + 8 <= dg; j += 8) {        // 8 independent row loads in flight
            int s0 = nbr[st + j],     s1 = nbr[st + j + 1];
            int s2 = nbr[st + j + 2], s3 = nbr[st + j + 3];
            int s4 = nbr[st + j + 4], s5 = nbr[st + j + 5];
            int s6 = nbr[st + j + 6], s7 = nbr[st + j + 7];
            bf16x8 r0 = *(const bf16x8*)(hb + (size_t)s0 * 128 + li * 8);
            bf16x8 r1 = *(const bf16x8*)(hb + (size_t)s1 * 128 + li * 8);
            bf16x8 r2 = *(const bf16x8*)(hb + (size_t)s2 * 128 + li * 8);
            bf16x8 r3 = *(const bf16x8*)(hb + (size_t)s3 * 128 + li * 8);
            bf16x8 r4 = *(const bf16x8*)(hb + (size_t)s4 * 128 + li * 8);
            bf16x8 r5 = *(const bf16x8*)(hb + (size_t)s5 * 128 + li * 8);
            bf16x8 r6 = *(const bf16x8*)(hb + (size_t)s6 * 128 + li * 8);
            bf16x8 r7 = *(const bf16x8*)(hb + (size_t)s7 * 128 + li * 8);
            acc8(a, r0); acc8(a, r1); acc8(a, r2); acc8(a, r3);
            acc8(a, r4); acc8(a, r5); acc8(a, r6); acc8(a, r7);
        }
        for (; j + 4 <= dg; j += 4) {
            int s0 = nbr[st + j],     s1 = nbr[st + j + 1];
            int s2 = nbr[st + j + 2], s3 = nbr[st + j + 3];
            bf16x8 r0 = *(const bf16x8*)(hb + (size_t)s0 * 128 + li * 8);
            bf16x8 r1 = *(const bf16x8*)(hb + (size_t)s1 * 128 + li * 8);
            bf16x8 r2 = *(const bf16x8*)(hb + (size_t)s2 * 128 + li * 8);
            bf16x8 r3 = *(const bf16x8*)(hb + (size_t)s3 * 128 + li * 8);
            acc8(a, r0); acc8(a, r1); acc8(a, r2); acc8(a, r3);
        }
        for (; j < dg; j++) {
            int s = nbr[st + j];
            bf16x8 r0 = *(const bf16x8*)(hb + (size_t)s * 128 + li * 8);
            acc8(a, r0);
        }
        float inv = 1.0f / fmaxf((float)dg, 1.0f);
        bf16x8 ov;
        ov[0] = (short)f2b(a[0] * inv); ov[1] = (short)f2b(a[1] * inv);
        ov[2] = (short)f2b(a[2] * inv); ov[3] = (short)f2b(a[3] * inv);
        ov[4] = (short)f2b(a[4] * inv); ov[5] = (short)f2b(a[5] * inv);
        ov[6] = (short)f2b(a[6] * inv); ov[7] = (short)f2b(a[7] * inv);
        *(bf16x8*)&A[r][li * 8] = ov;
    }
    __syncthreads();
    // ---- phase 1: MFMA over K=256 ----
    int m16 = l & 15, quad = l >> 4;
    int n0 = w * 32 + m16;
    int n1 = n0 + 16;
    floatx4 acc0 = {0.f, 0.f, 0.f, 0.f}, acc1 = {0.f, 0.f, 0.f, 0.f};
    for (int ks = 0; ks < 256; ks += 32) {
        bf16x8 a  = *(const bf16x8*)&A[m16][ks + quad * 8];
        bf16x8 b0 = *(const bf16x8*)(Wt + (size_t)n0 * 256 + ks + quad * 8);
        bf16x8 b1 = *(const bf16x8*)(Wt + (size_t)n1 * 256 + ks + quad * 8);
        acc0 = __builtin_amdgcn_mfma_f32_16x16x32_bf16(a, b0, acc0, 0, 0, 0);
        acc1 = __builtin_amdgcn_mfma_f32_16x16x32_bf16(a, b1, acc1, 0, 0, 0);
    }
#pragma unroll
    for (int i = 0; i < 4; i++) {
        H2[quad * 4 + i][n0] = acc0[i];
        H2[quad * 4 + i][n1] = acc1[i];
    }
    __syncthreads();
    // ---- phase 2: +bias, LN, gelu, gate; h3 -> h3b ----
    int d = l * 2;
    float bb0 = bl[d],  bb1 = bl[d + 1];
    float lw0 = lnw[d], lw1 = lnw[d + 1];
    float lb0 = lnb[d], lb1 = lnb[d + 1];
    float gw0 = gw[d],  gw1 = gw[d + 1];
    float gbias = gb[0];
#pragma unroll
    for (int rr = 0; rr < 4; rr++) {
        int r = w * 4 + rr;
        int row = row0 + r;
        if (row >= N) break;
        float v0 = H2[r][d] + bb0, v1 = H2[r][d + 1] + bb1;
        float s  = waveReduceSum(v0 + v1);
        float s2 = waveReduceSum(v0 * v0 + v1 * v1);
        float mu = s * (1.f / 128.f);
        float var = s2 * (1.f / 128.f) - mu * mu;
        float rstd = 1.0f / sqrtf(var + 1e-5f);
        float g0 = gelu_f((v0 - mu) * rstd * lw0 + lb0);
        float g1 = gelu_f((v1 - mu) * rstd * lw1 + lb1);
        float gp = waveReduceSum(g0 * gw0 + g1 * gw1);
        ushort2 ov; ov.x = f2b(g0); ov.y = f2b(g1);
        ((ushort2*)(h3b + (size_t)row * 128))[l] = ov;
        if (l == 0) gate[row] = gp + gbias;
    }
}

// ---------- 5. fused: segment bounds (binary search) + softmax pool + head ----------
__global__ void __launch_bounds__(128) k_attntail(
    const float* __restrict__ gate, const ushort_t* __restrict__ h3b,
    const int* __restrict__ batch,
    const float* __restrict__ text, const float* __restrict__ feats,
    const float* __restrict__ msgW, const float* __restrict__ msgb,
    const float* __restrict__ featW, const float* __restrict__ featb,
    const float* __restrict__ gwt, const float* __restrict__ mixw,
    const float* __restrict__ mixb, const float* __restrict__ fc1W,
    const float* __restrict__ fc1b,
    float* __restrict__ ge_out, float* __restrict__ attn_out,
    float* __restrict__ logits, int N, int G) {
    int g = blockIdx.x, t = threadIdx.x;
    __shared__ int sbound[2];
    __shared__ float wbuf[2];
    __shared__ float pbuf[128];
    __shared__ float txt[768];
    __shared__ float rbuf[4];
    if (t < 2) sbound[t] = lowerBound(batch, N, g + t);
    for (int i = t; i < 768; i += 128) txt[i] = text[(size_t)g * 768 + i];
    __syncthreads();
    int s0 = sbound[0], s1 = sbound[1];
    int lane = t & 63, wv = t >> 6;
    float acc = 0.f;
    if (s1 > s0) {                       // block-uniform branch
        float m = -3.0e38f;
        for (int i = s0 + t; i < s1; i += 128) m = fmaxf(m, gate[i]);
        m = waveReduceMax(m);
        if (lane == 0) wbuf[wv] = m;
        __syncthreads();
        m = fmaxf(wbuf[0], wbuf[1]);
        __syncthreads();
        float dsum = 0.f;
        for (int i = s0 + t; i < s1; i += 128) dsum += expf(gate[i] - m);
        dsum = waveReduceSum(dsum);
        if (lane == 0) wbuf[wv] = dsum;
        __syncthreads();
        float inv = 1.0f / (wbuf[0] + wbuf[1]);
        for (int base = s0; base < s1; base += 128) {
            int n = min(128, s1 - base);
            __syncthreads();
            if (t < n) {
                float p = expf(gate[base + t] - m) * inv;
                pbuf[t] = p;
                attn_out[base + t] = p;
            }
            __syncthreads();
            // PV: 4 independent accumulators, 4 row-loads in flight
            const ushort_t* hrow = h3b + (size_t)base * 128 + t;
            float ac0 = 0.f, ac1 = 0.f, ac2 = 0.f, ac3 = 0.f;
            int j = 0;
            for (; j + 4 <= n; j += 4) {
                ac0 += pbuf[j]     * b2f(hrow[(size_t)(j)     * 128]);
                ac1 += pbuf[j + 1] * b2f(hrow[(size_t)(j + 1) * 128]);
                ac2 += pbuf[j + 2] * b2f(hrow[(size_t)(j + 2) * 128]);
                ac3 += pbuf[j + 3] * b2f(hrow[(size_t)(j + 3) * 128]);
            }
            for (; j < n; j++)
                ac0 += pbuf[j] * b2f(hrow[(size_t)j * 128]);
            acc += (ac0 + ac1) + (ac2 + ac3);
        }
    }
    ge_out[(size_t)g * 128 + t] = acc;
    // ---- head ----
    float am = msgb[t];
    for (int k = 0; k < 768; k += 4) {
        float4 a = *(const float4*)&txt[k];
        am += a.x * msgW[(k + 0) * 128 + t] + a.y * msgW[(k + 1) * 128 + t]
            + a.z * msgW[(k + 2) * 128 + t] + a.w * msgW[(k + 3) * 128 + t];
    }
    float me = gelu_f(am);
    float af = featb[t];
#pragma unroll
    for (int k = 0; k < 14; k++) af += feats[g * 14 + k] * featW[k * 128 + t];
    float fe = gelu_f(af);
    float e0 = gwt[0] * acc;
    float ps = e0 + me + fe, ps2 = e0 * e0 + me * me + fe * fe;
    float r1 = waveReduceSum(ps), r2 = waveReduceSum(ps2);
    __syncthreads();
    if (lane == 0) { rbuf[wv] = r1; rbuf[2 + wv] = r2; }
    __syncthreads();
    float S = rbuf[0] + rbuf[1], S2 = rbuf[2] + rbuf[3];
    float mu = S * (1.f / 384.f);
    float var = S2 * (1.f / 384.f) - mu * mu;
    float rstd = 1.0f / sqrtf(var + 1e-5f);
    float n0 = (e0 - mu) * rstd * mixw[t]       + mixb[t];
    float n1 = (me - mu) * rstd * mixw[128 + t] + mixb[128 + t];
    float n2 = (fe - mu) * rstd * mixw[256 + t] + mixb[256 + t];
    float lp = n0 * fc1W[t] + n1 * fc1W[128 + t] + n2 * fc1W[256 + t];
    float r3 = waveReduceSum(lp);
    __syncthreads();
    if (lane == 0) rbuf[wv] = r3;
    __syncthreads();
    if (t == 0) logits[g] = rbuf[0] + rbuf[1] + fc1b[0];
}

// ---------- launch ----------
extern "C" void kernel_launch(void* const* d_in, const int* in_sizes, int n_in,
                              void* d_out, int out_size, void* d_ws, size_t ws_size,
                              hipStream_t stream) {
    const float* x     = (const float*)d_in[0];
    const int*   ei    = (const int*)d_in[1];
    const int*   batch = (const int*)d_in[2];
    const float* text  = (const float*)d_in[4];
    const float* feats = (const float*)d_in[5];
    const float* lnpw  = (const float*)d_in[6];
    const float* lnpb  = (const float*)d_in[7];
    const float* Wl    = (const float*)d_in[8];
    const float* bl    = (const float*)d_in[9];
    const float* Wr    = (const float*)d_in[10];
    const float* lncw  = (const float*)d_in[11];
    const float* lncb  = (const float*)d_in[12];
    const float* gatew = (const float*)d_in[13];
    const float* gateb = (const float*)d_in[14];
    const float* gwt   = (const float*)d_in[15];
    const float* msgW  = (const float*)d_in[16];
    const float* msgb  = (const float*)d_in[17];
    const float* featW = (const float*)d_in[18];
    const float* featb = (const float*)d_in[19];
    const float* mixw  = (const float*)d_in[20];
    const float* mixb  = (const float*)d_in[21];
    const float* fc1W  = (const float*)d_in[22];
    const float* fc1b  = (const float*)d_in[23];

    int N = in_sizes[0] / 128;
    int E = in_sizes[1] / 2;
    int G = in_sizes[4] / 768;

    char* wp = (char*)d_ws;
    auto alloc = [&](size_t bytes) -> char* {
        char* p = wp; wp += (bytes + 255) & ~(size_t)255; return p;
    };
    ushort_t* hb     = (ushort_t*)alloc((size_t)N * 128 * 2);   // h (bf16), read-only after cpl
    ushort_t* h3b    = (ushort_t*)alloc((size_t)N * 128 * 2);   // h3 (bf16) from aggemm
    ushort_t* Wt     = (ushort_t*)alloc(128 * 256 * 2);
    float*    gate   = (float*)alloc((size_t)N * 4);
    int*      deg    = (int*)alloc((size_t)N * 4);
    int*      cursor = (int*)alloc((size_t)N * 4);
    int*      wcur   = (int*)alloc((size_t)N * 4);
    int*      nbr    = (int*)alloc((size_t)E * 4);

    int nch  = (N + 255) / 256;    // 196 chunks of 256 nodes
    int ebc  = (E + 2047) / 2048;  // 8 edges/thread for count role (391)
    int ebc16 = (E + 4095) / 4096; // 16 edges/thread for place (196)

    // OUTPUTS fp32, flat in return order:
    float* logits_out = (float*)d_out;                 // [G, 1]
    float* ge_out     = logits_out + G;                // [G, 128]
    float* attn_out   = ge_out + (size_t)G * 128;      // [N, 1]

    hipMemsetAsync(deg, 0, (size_t)N * 4, stream);
    k_cpl      <<<ebc + 128 + (N + 3) / 4, 256, 0, stream>>>(
                                                   x, lnpw, lnpb, Wl, Wr, ei, deg,
                                                   Wt, hb, N, E, ebc);
    k_cursor3  <<<nch,               256, 0, stream>>>(deg, cursor, wcur, N);
    k_place    <<<ebc16,             256, 0, stream>>>(ei, wcur, nbr, E);
    k_aggemm   <<<(N + 15) / 16,     256, 0, stream>>>(hb, Wt, bl, lncw, lncb, gatew, gateb,
                                                       deg, cursor, nbr, h3b, gate, N);
    k_attntail <<<G,                 128, 0, stream>>>(gate, h3b, batch, text, feats,
                                                       msgW, msgb, featW, featb, gwt,
                                                       mixw, mixb, fc1W, fc1b,
                                                       ge_out, attn_out, logits_out, N, G);
}